// Round 26
// baseline (1529.261 us; speedup 1.0000x reference)
//
#include <hip/hip_runtime.h>
#include <hip/hip_bf16.h>

// Problem constants
#define B_   64
#define N_   200
#define S_   201
#define E_   128
#define H_   8
#define D_   16
#define HD_  128
#define FF_  512
#define L_   6
#define TWOH_ 16
#define NCH_  4             // n's per attn block
#define NCHB_ 51            // ceil(S_/NCH_)
#define PADM_ 209           // padded m stride for PL
#define QKVW_ 384           // fused QKV row width (f32)

typedef __hip_bfloat16 bf16;
typedef __attribute__((ext_vector_type(8))) short bfrag;   // 8 bf16 = 4 VGPRs
typedef __attribute__((ext_vector_type(8))) unsigned short ushort8;
typedef __attribute__((ext_vector_type(4))) float f32x4;

__device__ __forceinline__ void split_bf16(float v, bf16& h, bf16& l) {
  h = __float2bfloat16(v);
  l = __float2bfloat16(v - __bfloat162float(h));
}

// async global->LDS, 16B per lane; ldst must be wave-uniform (HW adds lane*16)
__device__ __forceinline__ void stage16(const bf16* g, bf16* l) {
  __builtin_amdgcn_global_load_lds(
      (const __attribute__((address_space(1))) void*)g,
      (__attribute__((address_space(3))) void*)l, 16, 0, 0);
}

// ---------------- initial embedding (also emits split-bf16 shadow for QKV mgemm) ----------------
__global__ void embed_kernel(const float* __restrict__ depot, const float* __restrict__ node,
                             const float* __restrict__ Wd, const float* __restrict__ bd,
                             const float* __restrict__ Wn, const float* __restrict__ bn,
                             float* __restrict__ X, bf16* __restrict__ XBh, bf16* __restrict__ XBl) {
  int idx = blockIdx.x * blockDim.x + threadIdx.x;
  if (idx >= B_ * S_ * E_) return;
  int e  = idx & (E_ - 1);
  int bs = idx >> 7;
  int s  = bs % S_;
  int b  = bs / S_;
  float acc;
  if (s == 0) {
    acc = bd[e];
    #pragma unroll
    for (int i = 0; i < 3; ++i) acc += depot[b * 3 + i] * Wd[i * E_ + e];
  } else {
    acc = bn[e];
    const float* nd = node + ((size_t)b * N_ + (s - 1)) * 4;
    #pragma unroll
    for (int i = 0; i < 4; ++i) acc += nd[i] * Wn[i * E_ + e];
  }
  X[idx] = acc;
  bf16 hh, ll;
  split_bf16(acc, hh, ll);
  XBh[idx] = hh;
  XBl[idx] = ll;
}

// ---------------- RA transpose+convert, direct gather: RAT[b][n][m][h] = bf16(RA[b][h][n][m]) ----
// Thread (b,n,m): 8 reads, each wave-coalesced over m; one contiguous 16B store. No LDS.
__global__ void racvt_kernel(const float* __restrict__ RA, bf16* __restrict__ RAT) {
  int idx = blockIdx.x * blockDim.x + threadIdx.x;
  if (idx >= B_ * S_ * S_) return;
  int m = idx % S_;
  int r = idx / S_;          // b*S + n
  int n = r % S_;
  int b = r / S_;
  ushort8 v;
  #pragma unroll
  for (int h = 0; h < H_; ++h) {
    float f = RA[(((size_t)b * H_ + h) * S_ + n) * S_ + m];
    v[h] = __builtin_bit_cast(unsigned short, __float2bfloat16(f));
  }
  *reinterpret_cast<ushort8*>(RAT + (size_t)idx * H_) = v;
}

// ---------------- weight transpose+convert to split bf16 (once per launch) ----------------
// layout (bf16 units): WoT 6x[128][128] @0 ; F1T 6x[512][128] @98304 ; F2T 6x[128][512] @491520
// QKVT 6x[384][128] @884736 (rows: 0-127 Wq, 128-255 Wk, 256-383 Wv)
__global__ void wcvt_kernel(const float* __restrict__ Wo, const float* __restrict__ F1w,
                            const float* __restrict__ F2w, const float* __restrict__ Wq,
                            const float* __restrict__ Wk, const float* __restrict__ Wv,
                            bf16* __restrict__ WTh, bf16* __restrict__ WTl) {
  int idx = blockIdx.x * blockDim.x + threadIdx.x;
  if (idx >= 1179648) return;
  float v;
  if (idx < 98304) {
    int l = idx / 16384, rr = idx % 16384;
    int e = rr / 128, h = rr % 128;
    v = Wo[(size_t)l * 16384 + h * 128 + e];
  } else if (idx < 491520) {
    int rem = idx - 98304;
    int l = rem / 65536, rr = rem % 65536;
    int f = rr / 128, e = rr % 128;
    v = F1w[(size_t)l * 65536 + e * 512 + f];
  } else if (idx < 884736) {
    int rem = idx - 491520;
    int l = rem / 65536, rr = rem % 65536;
    int e = rr / 512, f = rr % 512;
    v = F2w[(size_t)l * 65536 + f * 128 + e];
  } else {
    int rem = idx - 884736;
    int l = rem / 49152, rr = rem % 49152;   // [384][128] per layer
    int n = rr / 128, e = rr % 128;
    const float* src = (n < 128) ? Wq : (n < 256) ? Wk : Wv;
    int hd = n & 127;
    v = src[(size_t)l * 16384 + e * 128 + hd];
  }
  bf16 h, l2;
  split_bf16(v, h, l2);
  WTh[idx] = h;
  WTl[idx] = l2;
}

// ---------------- split-precision MFMA GEMM, 64x64 tile (r22-proven) ----------------
// C = A@B (+bias)(+res) with A = Ah+Al (row stride lda bf16), B^T rows = BTh+BTl (stride K).
// acc += ah*bh + ah*bl + al*bh  (al*bl dropped, ~2^-18 rel)
// EPI 1: f32 out (bias+res). EPI 2: relu(bias) -> split bf16 out. EPI 3: plain f32 out.
template<int EPI>
__global__ __launch_bounds__(256) void mgemm_kernel(
    const bf16* __restrict__ Ah, const bf16* __restrict__ Al,
    const bf16* __restrict__ BTh, const bf16* __restrict__ BTl,
    const float* __restrict__ bias, const float* __restrict__ res,
    float* __restrict__ Cf, bf16* __restrict__ Cbh, bf16* __restrict__ Cbl,
    int K, int Ntot, int lda) {
  __shared__ __align__(16) bf16 Ash[4096];
  __shared__ __align__(16) bf16 Asl[4096];
  __shared__ __align__(16) bf16 Bsh[4096];
  __shared__ __align__(16) bf16 Bsl[4096];
  int tid = threadIdx.x;
  int m0 = blockIdx.x * 64, n0 = blockIdx.y * 64;
  int lane = tid & 63, wave = tid >> 6;
  int wr = wave >> 1, wc = wave & 1;
  int la = lane & 15, lb = lane >> 4;
  // staging geometry: wave covers rows [wave*16, wave*16+16), 2 chunks of 8 rows
  int lrow = lane >> 3;                       // 0..7 row-within-chunk
  int cbl  = (lane & 7) ^ (lrow & 7);         // logical col-block (inverse-swizzled source)
  f32x4 acc[2][2] = {};
  for (int k0 = 0; k0 < K; k0 += 64) {
    #pragma unroll
    for (int c = 0; c < 2; ++c) {
      int rr = wave * 16 + c * 8 + lrow;
      size_t ga = (size_t)(m0 + rr) * lda + k0 + cbl * 8;
      size_t gb = (size_t)(n0 + rr) * K + k0 + cbl * 8;
      int lo = wave * 1024 + c * 512;         // bf16 units
      stage16(Ah + ga, Ash + lo);
      stage16(Al + ga, Asl + lo);
      stage16(BTh + gb, Bsh + lo);
      stage16(BTl + gb, Bsl + lo);
    }
    __syncthreads();   // drains vmcnt -> LDS ready
    #pragma unroll
    for (int ks = 0; ks < 64; ks += 32) {
      int cb0 = (ks >> 3) + lb;               // logical col-block of this fragment
      auto rd = [&](const bf16* buf, int r) {
        return *reinterpret_cast<const bfrag*>(&buf[r * 64 + ((cb0 ^ (r & 7)) << 3)]);
      };
      int ra0 = wr * 32 + la, ra1 = ra0 + 16;
      int rb0 = wc * 32 + la, rb1 = rb0 + 16;
      bfrag ah0 = rd(Ash, ra0), ah1 = rd(Ash, ra1);
      bfrag al0 = rd(Asl, ra0), al1 = rd(Asl, ra1);
      bfrag bh0 = rd(Bsh, rb0), bh1 = rd(Bsh, rb1);
      bfrag bl0 = rd(Bsl, rb0), bl1 = rd(Bsl, rb1);
      acc[0][0] = __builtin_amdgcn_mfma_f32_16x16x32_bf16(ah0, bh0, acc[0][0], 0, 0, 0);
      acc[0][0] = __builtin_amdgcn_mfma_f32_16x16x32_bf16(ah0, bl0, acc[0][0], 0, 0, 0);
      acc[0][0] = __builtin_amdgcn_mfma_f32_16x16x32_bf16(al0, bh0, acc[0][0], 0, 0, 0);
      acc[0][1] = __builtin_amdgcn_mfma_f32_16x16x32_bf16(ah0, bh1, acc[0][1], 0, 0, 0);
      acc[0][1] = __builtin_amdgcn_mfma_f32_16x16x32_bf16(ah0, bl1, acc[0][1], 0, 0, 0);
      acc[0][1] = __builtin_amdgcn_mfma_f32_16x16x32_bf16(al0, bh1, acc[0][1], 0, 0, 0);
      acc[1][0] = __builtin_amdgcn_mfma_f32_16x16x32_bf16(ah1, bh0, acc[1][0], 0, 0, 0);
      acc[1][0] = __builtin_amdgcn_mfma_f32_16x16x32_bf16(ah1, bl0, acc[1][0], 0, 0, 0);
      acc[1][0] = __builtin_amdgcn_mfma_f32_16x16x32_bf16(al1, bh0, acc[1][0], 0, 0, 0);
      acc[1][1] = __builtin_amdgcn_mfma_f32_16x16x32_bf16(ah1, bh1, acc[1][1], 0, 0, 0);
      acc[1][1] = __builtin_amdgcn_mfma_f32_16x16x32_bf16(ah1, bl1, acc[1][1], 0, 0, 0);
      acc[1][1] = __builtin_amdgcn_mfma_f32_16x16x32_bf16(al1, bh1, acc[1][1], 0, 0, 0);
    }
    __syncthreads();
  }
  // epilogue: C/D layout col=lane&15, row=(lane>>4)*4+j  [m89-verified]
  int r0 = lb * 4;
  #pragma unroll
  for (int ti = 0; ti < 2; ++ti)
    #pragma unroll
    for (int tj = 0; tj < 2; ++tj)
      #pragma unroll
      for (int j = 0; j < 4; ++j) {
        int m = m0 + wr * 32 + ti * 16 + r0 + j;
        int n = n0 + wc * 32 + tj * 16 + la;
        float v = acc[ti][tj][j];
        if (EPI == 1) {
          v += bias[n] + res[(size_t)m * Ntot + n];
          Cf[(size_t)m * Ntot + n] = v;
        } else if (EPI == 2) {
          v += bias[n];
          v = v > 0.f ? v : 0.f;
          bf16 vh, vl;
          split_bf16(v, vh, vl);
          Cbh[(size_t)m * Ntot + n] = vh;
          Cbl[(size_t)m * Ntot + n] = vl;
        } else {
          Cf[(size_t)m * Ntot + n] = v;
        }
      }
}

// ---------------- fused: inline scores (cooperative, LDS) + edge-MLP + softmax + PV ----------------
// RA loads hoisted to kernel top (latency hides under score phases 0a/0b).
__global__ __launch_bounds__(256) void attn_kernel(
    const bf16* __restrict__ RAT,
    const float* __restrict__ A1w, const float* __restrict__ A1b,
    const float* __restrict__ A2w, const float* __restrict__ A2b,
    float* __restrict__ QKV) {
  int blk = blockIdx.x;
  int b  = blk / NCHB_;
  int n0 = (blk % NCHB_) * NCH_;
  int NV = min(NCH_, S_ - n0);
  __shared__ float PL[NCH_][H_][PADM_];
  __shared__ float shbuf[1056];   // union: qs[4][128] (ph0) / partial[2][4][8][16] (ph3); inv @1024
  float* qs  = shbuf;
  float* inv = shbuf + 1024;
  int tid = threadIdx.x;

  // ---- prologue: issue RA loads for all 4 slots (consumed in phase 1) ----
  ushort8 rv[4];
  int   mm[4], nnv[4];
  bool  val[4];
  {
    #pragma unroll
    for (int s = 0; s < 4; ++s) {
      int e = tid + s * 256;
      val[s] = (e < NV * S_);
      int nn = e / S_;
      int m  = e - nn * S_;
      if (!val[s]) { nn = 0; m = 0; }   // clamp: address stays in-bounds
      nnv[s] = nn; mm[s] = m;
      rv[s] = *reinterpret_cast<const ushort8*>(
          RAT + (((size_t)b * S_ + (n0 + nn)) * S_ + m) * H_);
    }
  }

  // ---- phase 0a: stage q rows ----
  for (int p = tid; p < NV * HD_; p += 256) {
    int nn = p >> 7, d = p & 127;
    qs[nn * HD_ + d] = QKV[((size_t)(b * S_ + n0 + nn)) * QKVW_ + d];
  }
  __syncthreads();

  // ---- phase 0b: scores into PL (k loaded once per (h,m), reused across 4 n's) ----
  for (int p = tid; p < H_ * S_; p += 256) {
    int h = p / S_, m = p - h * S_;
    const float* kp = QKV + ((size_t)(b * S_ + m)) * QKVW_ + 128 + h * D_;
    f32x4 k0 = *(const f32x4*)(kp + 0);
    f32x4 k1 = *(const f32x4*)(kp + 4);
    f32x4 k2 = *(const f32x4*)(kp + 8);
    f32x4 k3 = *(const f32x4*)(kp + 12);
    #pragma unroll
    for (int nn = 0; nn < NCH_; ++nn) {
      const float* q = qs + nn * HD_ + h * D_;
      float a = 0.f;
      #pragma unroll
      for (int c = 0; c < 4; ++c) a += q[c] * k0[c];
      #pragma unroll
      for (int c = 0; c < 4; ++c) a += q[4 + c] * k1[c];
      #pragma unroll
      for (int c = 0; c < 4; ++c) a += q[8 + c] * k2[c];
      #pragma unroll
      for (int c = 0; c < 4; ++c) a += q[12 + c] * k3[c];
      PL[nn][h][m] = a;
    }
  }
  __syncthreads();

  // ---- phase 1: MLP per slot (scores from PL, RA from prefetched rv) ----
  {
    float cc[4][TWOH_];
    #pragma unroll
    for (int s = 0; s < 4; ++s) {
      #pragma unroll
      for (int h = 0; h < H_; ++h) {
        cc[s][h] = PL[nnv[s]][h][mm[s]];
        unsigned int u = ((unsigned int)rv[s][h]) << 16;
        cc[s][H_ + h] = __builtin_bit_cast(float, u);
      }
    }
    #pragma unroll
    for (int s = 0; s < 4; ++s) {
      if (!val[s]) continue;
      float h1[TWOH_];
      #pragma unroll
      for (int j = 0; j < TWOH_; ++j) h1[j] = A1b[j];        // uniform -> s_load
      #pragma unroll
      for (int i = 0; i < TWOH_; ++i) {
        float c = cc[s][i];
        #pragma unroll
        for (int j = 0; j < TWOH_; ++j)
          h1[j] += c * A1w[i * TWOH_ + j];                   // uniform -> SGPR operand
      }
      float agg[H_];
      #pragma unroll
      for (int h = 0; h < H_; ++h) agg[h] = A2b[h];
      #pragma unroll
      for (int j = 0; j < TWOH_; ++j) {
        float r = fmaxf(h1[j], 0.f);
        #pragma unroll
        for (int h = 0; h < H_; ++h)
          agg[h] += r * A2w[j * H_ + h];
      }
      #pragma unroll
      for (int h = 0; h < H_; ++h) PL[nnv[s]][h][mm[s]] = agg[h];
    }
  }
  __syncthreads();

  // ---- phase 2: softmax over m; 32 groups (nn,h) x 8 lanes ----
  {
    int g = tid >> 3, lane = tid & 7;
    int nn = g >> 3, h = g & 7;
    if (nn < NV) {
      float mx = -1e30f;
      for (int m = lane; m < S_; m += 8) mx = fmaxf(mx, PL[nn][h][m]);
      #pragma unroll
      for (int off = 4; off > 0; off >>= 1) mx = fmaxf(mx, __shfl_xor(mx, off, 8));
      float sum = 0.f;
      for (int m = lane; m < S_; m += 8) {
        float e = __expf(PL[nn][h][m] - mx);
        PL[nn][h][m] = e;
        sum += e;
      }
      #pragma unroll
      for (int off = 4; off > 0; off >>= 1) sum += __shfl_xor(sum, off, 8);
      if (lane == 0) inv[nn * H_ + h] = 1.f / sum;
    }
  }
  __syncthreads();

  // ---- phase 3: PV, all 256 threads: (m-parity) x (h,d), 4 n-accumulators per V load ----
  float (*partial)[NCH_][H_][D_] = (float (*)[NCH_][H_][D_])shbuf;
  {
    int half = tid >> 7, h = (tid >> 4) & 7, d = tid & 15;
    float a0 = 0.f, a1 = 0.f, a2 = 0.f, a3 = 0.f;
    const float* vp = QKV + (size_t)b * S_ * QKVW_ + 256 + h * D_ + d;
    for (int m = half; m < S_; m += 2) {
      float vv = vp[(size_t)m * QKVW_];
      a0 += PL[0][h][m] * vv;
      a1 += PL[1][h][m] * vv;
      a2 += PL[2][h][m] * vv;
      a3 += PL[3][h][m] * vv;
    }
    partial[half][0][h][d] = a0;
    partial[half][1][h][d] = a1;
    partial[half][2][h][d] = a2;
    partial[half][3][h][d] = a3;
  }
  __syncthreads();
  if (tid < 128) {
    int h = tid >> 4, d = tid & 15;
    #pragma unroll
    for (int nn = 0; nn < NCH_; ++nn)
      if (nn < NV) {
        float s = (partial[0][nn][h][d] + partial[1][nn][h][d]) * inv[nn * H_ + h];
        bf16* ob = (bf16*)(QKV + (size_t)(b * S_ + n0 + nn) * QKVW_);
        bf16 sh, sl;
        split_bf16(s, sh, sl);
        ob[h * D_ + d]       = sh;   // OBh in Q cols [0,64) f32
        ob[128 + h * D_ + d] = sl;   // OBl in Q cols [64,128) f32
      }
  }
}

// ---------------- instance norm, (B,4) grid: 32 channels per block ----------------
__global__ __launch_bounds__(128) void inorm_kernel(const float* __restrict__ Y,
                                                    const float* __restrict__ w,
                                                    const float* __restrict__ bb,
                                                    float* __restrict__ X,
                                                    bf16* __restrict__ XBh,
                                                    bf16* __restrict__ XBl) {
  int b = blockIdx.x;
  int e0 = blockIdx.y * 32;
  int tid = threadIdx.x;
  int el = tid & 31, sg = tid >> 5;   // 4 s-groups x 32 channels
  int e = e0 + el;
  __shared__ float ps[4][32], pss[4][32];
  const float* base = Y + (size_t)b * S_ * E_;
  float s = 0.f, ss = 0.f;
  for (int i = sg; i < S_; i += 4) {
    float v = base[(size_t)i * E_ + e];
    s += v; ss += v * v;
  }
  ps[sg][el] = s; pss[sg][el] = ss;
  __syncthreads();
  if (sg == 0) {
    s  = ps[0][el] + ps[1][el] + ps[2][el] + ps[3][el];
    ss = pss[0][el] + pss[1][el] + pss[2][el] + pss[3][el];
    float mean = s / S_;
    float var  = fmaxf(ss / S_ - mean * mean, 0.f);
    float scale = rsqrtf(var + 1e-5f) * w[e];
    ps[0][el]  = scale;
    pss[0][el] = bb[e] - mean * scale;
  }
  __syncthreads();
  float scale = ps[0][el], shift = pss[0][el];
  float* dst = X + (size_t)b * S_ * E_;
  for (int i = sg; i < S_; i += 4) {
    size_t idx = (size_t)i * E_ + e;
    float v = base[idx] * scale + shift;
    dst[idx] = v;
    if (XBh) {
      size_t gi = (size_t)b * S_ * E_ + idx;
      bf16 vh, vl;
      split_bf16(v, vh, vl);
      XBh[gi] = vh;
      XBl[gi] = vl;
    }
  }
}

extern "C" void kernel_launch(void* const* d_in, const int* in_sizes, int n_in,
                              void* d_out, int out_size, void* d_ws, size_t ws_size,
                              hipStream_t stream) {
  const float* depot = (const float*)d_in[0];
  const float* node  = (const float*)d_in[1];
  const float* RA    = (const float*)d_in[2];
  const float* Wd    = (const float*)d_in[3];
  const float* bd    = (const float*)d_in[4];
  const float* Wn    = (const float*)d_in[5];
  const float* bn    = (const float*)d_in[6];
  const float* Wq    = (const float*)d_in[7];
  const float* Wk    = (const float*)d_in[8];
  const float* Wv    = (const float*)d_in[9];
  const float* Wo    = (const float*)d_in[10];
  const float* bo    = (const float*)d_in[11];
  const float* A1w   = (const float*)d_in[12];
  const float* A1b   = (const float*)d_in[13];
  const float* A2w   = (const float*)d_in[14];
  const float* A2b   = (const float*)d_in[15];
  const float* n1w   = (const float*)d_in[16];
  const float* n1b   = (const float*)d_in[17];
  const float* n2w   = (const float*)d_in[18];
  const float* n2b   = (const float*)d_in[19];
  const float* F1w   = (const float*)d_in[20];
  const float* F1b   = (const float*)d_in[21];
  const float* F2w   = (const float*)d_in[22];
  const float* F2b   = (const float*)d_in[23];

  const size_t XSZ  = (size_t)B_ * S_ * E_;        // 1,646,592
  const size_t SCSZ = (size_t)B_ * H_ * S_ * S_;   // 20,685,312 (scratch region)
  const size_t XBF  = XSZ / 2;                     // bf16 buffer in float-slots: 823,296
  float* ws = (float*)d_ws;
  float* X   = ws;                    // f32 [M][E]
  float* QKV = ws + XSZ;              // f32 [M][384] packed Q|K|V (OB reuses dead Q cols)
  float* SCR = ws + 4 * XSZ;          // scratch region:
  float* TMP = SCR;                                  // f32 [0, XSZ)
  bf16*  XBh = (bf16*)(SCR + XSZ);                   // M*E bf16
  bf16*  XBl = (bf16*)(SCR + XSZ + XBF);
  bf16*  HBh = (bf16*)(SCR + XSZ + 2 * XBF);         // M*FF bf16 (4 XBF span)
  bf16*  HBl = (bf16*)(SCR + XSZ + 6 * XBF);
  bf16*  RAT = (bf16*)(SCR + XSZ + 10 * XBF);        // B*S*S*H bf16 (10.34M slots, fits SCSZ)
  float* tail = ws + 4 * XSZ + SCSZ;
  bf16*  WTh = (bf16*)tail;                          // 1,179,648 bf16 = 589,824 fl
  bf16*  WTl = (bf16*)(tail + 589824);
  // ws use: 4*XSZ + SCSZ + 1,179,648 floats = 28,451,328 fl = 113.8 MB
  const bf16* OBh = (const bf16*)QKV;        // strided lda=768 (row = 384 f32)
  const bf16* OBl = (const bf16*)QKV + 128;

  const int M = B_ * S_;  // 12864 = 201*64

  wcvt_kernel<<<4608, 256, 0, stream>>>(Wo, F1w, F2w, Wq, Wk, Wv, WTh, WTl);
  racvt_kernel<<<(B_ * S_ * S_ + 255) / 256, 256, 0, stream>>>(RA, RAT);
  embed_kernel<<<(B_ * S_ * E_ + 255) / 256, 256, 0, stream>>>(depot, node, Wd, bd, Wn, bn, X, XBh, XBl);

  for (int l = 0; l < L_; ++l) {
    // QKV fused: [M][384] = XB @ [Wq|Wk|Wv]  (split precision)
    mgemm_kernel<3><<<dim3(M / 64, 6), 256, 0, stream>>>(
        XBh, XBl, WTh + 884736 + (size_t)l * 49152, WTl + 884736 + (size_t)l * 49152,
        nullptr, nullptr, QKV, nullptr, nullptr, E_, QKVW_, E_);
    // fused inline-score + edge-MLP + softmax + PV
    attn_kernel<<<B_ * NCHB_, 256, 0, stream>>>(RAT,
        A1w + (size_t)l * TWOH_ * TWOH_, A1b + (size_t)l * TWOH_,
        A2w + (size_t)l * TWOH_ * H_,    A2b + (size_t)l * H_, QKV);
    // Wo: TMP = OB @ WoT^T + bo + X   (split precision; A strided in QKV rows)
    mgemm_kernel<1><<<dim3(M / 64, 2), 256, 0, stream>>>(
        OBh, OBl, WTh + (size_t)l * 16384, WTl + (size_t)l * 16384,
        bo + (size_t)l * E_, X, TMP, nullptr, nullptr, HD_, E_, 768);
    inorm_kernel<<<dim3(B_, 4), 128, 0, stream>>>(TMP, n1w + (size_t)l * E_, n1b + (size_t)l * E_, X, XBh, XBl);
    // F1: HB = relu(XB @ F1T^T + F1b)  (split bf16 out)
    mgemm_kernel<2><<<dim3(M / 64, 8), 256, 0, stream>>>(
        XBh, XBl, WTh + 98304 + (size_t)l * 65536, WTl + 98304 + (size_t)l * 65536,
        F1b + (size_t)l * FF_, nullptr, nullptr, HBh, HBl, E_, FF_, E_);
    // F2: TMP = HB @ F2T^T + F2b + X
    mgemm_kernel<1><<<dim3(M / 64, 2), 256, 0, stream>>>(
        HBh, HBl, WTh + 491520 + (size_t)l * 65536, WTl + 491520 + (size_t)l * 65536,
        F2b + (size_t)l * E_, X, TMP, nullptr, nullptr, FF_, E_, FF_);
    float* dst = (l == L_ - 1) ? (float*)d_out : X;
    bf16* xh = (l == L_ - 1) ? nullptr : XBh;
    bf16* xl = (l == L_ - 1) ? nullptr : XBl;
    inorm_kernel<<<dim3(B_, 4), 128, 0, stream>>>(TMP, n2w + (size_t)l * E_, n2b + (size_t)l * E_, dst, xh, xl);
  }
}

// Round 27
// 1352.493 us; speedup vs baseline: 1.1307x; 1.1307x over previous
//
#include <hip/hip_runtime.h>
#include <hip/hip_bf16.h>

// Problem constants
#define B_   64
#define N_   200
#define S_   201
#define E_   128
#define H_   8
#define D_   16
#define HD_  128
#define FF_  512
#define L_   6
#define TWOH_ 16
#define NCH_  4             // n's per attn block
#define NCHB_ 51            // ceil(S_/NCH_)
#define PADM_ 209           // padded m stride for PL
#define QKVW_ 384           // fused QKV row width (f32)

typedef __hip_bfloat16 bf16;
typedef __attribute__((ext_vector_type(8))) short bfrag;   // 8 bf16 = 4 VGPRs
typedef __attribute__((ext_vector_type(8))) unsigned short ushort8;
typedef __attribute__((ext_vector_type(4))) float f32x4;

__device__ __forceinline__ void split_bf16(float v, bf16& h, bf16& l) {
  h = __float2bfloat16(v);
  l = __float2bfloat16(v - __bfloat162float(h));
}

// async global->LDS, 16B per lane; ldst must be wave-uniform (HW adds lane*16)
__device__ __forceinline__ void stage16(const bf16* g, bf16* l) {
  __builtin_amdgcn_global_load_lds(
      (const __attribute__((address_space(1))) void*)g,
      (__attribute__((address_space(3))) void*)l, 16, 0, 0);
}

// ---------------- initial embedding (also emits split-bf16 shadow for QKV mgemm) ----------------
__global__ void embed_kernel(const float* __restrict__ depot, const float* __restrict__ node,
                             const float* __restrict__ Wd, const float* __restrict__ bd,
                             const float* __restrict__ Wn, const float* __restrict__ bn,
                             float* __restrict__ X, bf16* __restrict__ XBh, bf16* __restrict__ XBl) {
  int idx = blockIdx.x * blockDim.x + threadIdx.x;
  if (idx >= B_ * S_ * E_) return;
  int e  = idx & (E_ - 1);
  int bs = idx >> 7;
  int s  = bs % S_;
  int b  = bs / S_;
  float acc;
  if (s == 0) {
    acc = bd[e];
    #pragma unroll
    for (int i = 0; i < 3; ++i) acc += depot[b * 3 + i] * Wd[i * E_ + e];
  } else {
    acc = bn[e];
    const float* nd = node + ((size_t)b * N_ + (s - 1)) * 4;
    #pragma unroll
    for (int i = 0; i < 4; ++i) acc += nd[i] * Wn[i * E_ + e];
  }
  X[idx] = acc;
  bf16 hh, ll;
  split_bf16(acc, hh, ll);
  XBh[idx] = hh;
  XBl[idx] = ll;
}

// ---------------- weight transpose+convert to split bf16 (once per launch) ----------------
// layout (bf16 units): WoT 6x[128][128] @0 ; F1T 6x[512][128] @98304 ; F2T 6x[128][512] @491520
// QKVT 6x[384][128] @884736 (rows: 0-127 Wq, 128-255 Wk, 256-383 Wv)
__global__ void wcvt_kernel(const float* __restrict__ Wo, const float* __restrict__ F1w,
                            const float* __restrict__ F2w, const float* __restrict__ Wq,
                            const float* __restrict__ Wk, const float* __restrict__ Wv,
                            bf16* __restrict__ WTh, bf16* __restrict__ WTl) {
  int idx = blockIdx.x * blockDim.x + threadIdx.x;
  if (idx >= 1179648) return;
  float v;
  if (idx < 98304) {
    int l = idx / 16384, rr = idx % 16384;
    int e = rr / 128, h = rr % 128;
    v = Wo[(size_t)l * 16384 + h * 128 + e];
  } else if (idx < 491520) {
    int rem = idx - 98304;
    int l = rem / 65536, rr = rem % 65536;
    int f = rr / 128, e = rr % 128;
    v = F1w[(size_t)l * 65536 + e * 512 + f];
  } else if (idx < 884736) {
    int rem = idx - 491520;
    int l = rem / 65536, rr = rem % 65536;
    int e = rr / 512, f = rr % 512;
    v = F2w[(size_t)l * 65536 + f * 128 + e];
  } else {
    int rem = idx - 884736;
    int l = rem / 49152, rr = rem % 49152;   // [384][128] per layer
    int n = rr / 128, e = rr % 128;
    const float* src = (n < 128) ? Wq : (n < 256) ? Wk : Wv;
    int hd = n & 127;
    v = src[(size_t)l * 16384 + e * 128 + hd];
  }
  bf16 h, l2;
  split_bf16(v, h, l2);
  WTh[idx] = h;
  WTl[idx] = l2;
}

// ---------------- split-precision MFMA GEMM, 64x64 tile (r22-proven) ----------------
// C = A@B (+bias)(+res) with A = Ah+Al (row stride lda bf16), B^T rows = BTh+BTl (stride K).
// acc += ah*bh + ah*bl + al*bh  (al*bl dropped, ~2^-18 rel)
// EPI 1: f32 out (bias+res). EPI 2: relu(bias) -> split bf16 out. EPI 3: plain f32 out.
template<int EPI>
__global__ __launch_bounds__(256) void mgemm_kernel(
    const bf16* __restrict__ Ah, const bf16* __restrict__ Al,
    const bf16* __restrict__ BTh, const bf16* __restrict__ BTl,
    const float* __restrict__ bias, const float* __restrict__ res,
    float* __restrict__ Cf, bf16* __restrict__ Cbh, bf16* __restrict__ Cbl,
    int K, int Ntot, int lda) {
  __shared__ __align__(16) bf16 Ash[4096];
  __shared__ __align__(16) bf16 Asl[4096];
  __shared__ __align__(16) bf16 Bsh[4096];
  __shared__ __align__(16) bf16 Bsl[4096];
  int tid = threadIdx.x;
  int m0 = blockIdx.x * 64, n0 = blockIdx.y * 64;
  int lane = tid & 63, wave = tid >> 6;
  int wr = wave >> 1, wc = wave & 1;
  int la = lane & 15, lb = lane >> 4;
  // staging geometry: wave covers rows [wave*16, wave*16+16), 2 chunks of 8 rows
  int lrow = lane >> 3;                       // 0..7 row-within-chunk
  int cbl  = (lane & 7) ^ (lrow & 7);         // logical col-block (inverse-swizzled source)
  f32x4 acc[2][2] = {};
  for (int k0 = 0; k0 < K; k0 += 64) {
    #pragma unroll
    for (int c = 0; c < 2; ++c) {
      int rr = wave * 16 + c * 8 + lrow;
      size_t ga = (size_t)(m0 + rr) * lda + k0 + cbl * 8;
      size_t gb = (size_t)(n0 + rr) * K + k0 + cbl * 8;
      int lo = wave * 1024 + c * 512;         // bf16 units
      stage16(Ah + ga, Ash + lo);
      stage16(Al + ga, Asl + lo);
      stage16(BTh + gb, Bsh + lo);
      stage16(BTl + gb, Bsl + lo);
    }
    __syncthreads();   // drains vmcnt -> LDS ready
    #pragma unroll
    for (int ks = 0; ks < 64; ks += 32) {
      int cb0 = (ks >> 3) + lb;               // logical col-block of this fragment
      auto rd = [&](const bf16* buf, int r) {
        return *reinterpret_cast<const bfrag*>(&buf[r * 64 + ((cb0 ^ (r & 7)) << 3)]);
      };
      int ra0 = wr * 32 + la, ra1 = ra0 + 16;
      int rb0 = wc * 32 + la, rb1 = rb0 + 16;
      bfrag ah0 = rd(Ash, ra0), ah1 = rd(Ash, ra1);
      bfrag al0 = rd(Asl, ra0), al1 = rd(Asl, ra1);
      bfrag bh0 = rd(Bsh, rb0), bh1 = rd(Bsh, rb1);
      bfrag bl0 = rd(Bsl, rb0), bl1 = rd(Bsl, rb1);
      acc[0][0] = __builtin_amdgcn_mfma_f32_16x16x32_bf16(ah0, bh0, acc[0][0], 0, 0, 0);
      acc[0][0] = __builtin_amdgcn_mfma_f32_16x16x32_bf16(ah0, bl0, acc[0][0], 0, 0, 0);
      acc[0][0] = __builtin_amdgcn_mfma_f32_16x16x32_bf16(al0, bh0, acc[0][0], 0, 0, 0);
      acc[0][1] = __builtin_amdgcn_mfma_f32_16x16x32_bf16(ah0, bh1, acc[0][1], 0, 0, 0);
      acc[0][1] = __builtin_amdgcn_mfma_f32_16x16x32_bf16(ah0, bl1, acc[0][1], 0, 0, 0);
      acc[0][1] = __builtin_amdgcn_mfma_f32_16x16x32_bf16(al0, bh1, acc[0][1], 0, 0, 0);
      acc[1][0] = __builtin_amdgcn_mfma_f32_16x16x32_bf16(ah1, bh0, acc[1][0], 0, 0, 0);
      acc[1][0] = __builtin_amdgcn_mfma_f32_16x16x32_bf16(ah1, bl0, acc[1][0], 0, 0, 0);
      acc[1][0] = __builtin_amdgcn_mfma_f32_16x16x32_bf16(al1, bh0, acc[1][0], 0, 0, 0);
      acc[1][1] = __builtin_amdgcn_mfma_f32_16x16x32_bf16(ah1, bh1, acc[1][1], 0, 0, 0);
      acc[1][1] = __builtin_amdgcn_mfma_f32_16x16x32_bf16(ah1, bl1, acc[1][1], 0, 0, 0);
      acc[1][1] = __builtin_amdgcn_mfma_f32_16x16x32_bf16(al1, bh1, acc[1][1], 0, 0, 0);
    }
    __syncthreads();
  }
  // epilogue: C/D layout col=lane&15, row=(lane>>4)*4+j  [m89-verified]
  int r0 = lb * 4;
  #pragma unroll
  for (int ti = 0; ti < 2; ++ti)
    #pragma unroll
    for (int tj = 0; tj < 2; ++tj)
      #pragma unroll
      for (int j = 0; j < 4; ++j) {
        int m = m0 + wr * 32 + ti * 16 + r0 + j;
        int n = n0 + wc * 32 + tj * 16 + la;
        float v = acc[ti][tj][j];
        if (EPI == 1) {
          v += bias[n] + res[(size_t)m * Ntot + n];
          Cf[(size_t)m * Ntot + n] = v;
        } else if (EPI == 2) {
          v += bias[n];
          v = v > 0.f ? v : 0.f;
          bf16 vh, vl;
          split_bf16(v, vh, vl);
          Cbh[(size_t)m * Ntot + n] = vh;
          Cbl[(size_t)m * Ntot + n] = vl;
        } else {
          Cf[(size_t)m * Ntot + n] = v;
        }
      }
}

// ---------------- fused: inline scores (cooperative, LDS) + edge-MLP + softmax + PV ----------------
// MODE 0 (layer 0): RA read scattered f32 (r22-proven pattern), bf16-rounded, RAT written
//                   (one coalesced 16B store per edge). MLP uses the bf16-rounded values.
// MODE 1 (layers 1+): RA read from RAT as one 16B bf16x8 load per edge (r25-proven, 138us).
template<int MODE>
__global__ __launch_bounds__(256) void attn_kernel(
    const float* __restrict__ RA, bf16* __restrict__ RAT,
    const float* __restrict__ A1w, const float* __restrict__ A1b,
    const float* __restrict__ A2w, const float* __restrict__ A2b,
    float* __restrict__ QKV) {
  int blk = blockIdx.x;
  int b  = blk / NCHB_;
  int n0 = (blk % NCHB_) * NCH_;
  int NV = min(NCH_, S_ - n0);
  __shared__ float PL[NCH_][H_][PADM_];
  __shared__ float shbuf[1056];   // union: qs[4][128] (ph0) / partial[2][4][8][16] (ph3); inv @1024
  float* qs  = shbuf;
  float* inv = shbuf + 1024;
  int tid = threadIdx.x;

  // ---- phase 0a: stage q rows ----
  for (int p = tid; p < NV * HD_; p += 256) {
    int nn = p >> 7, d = p & 127;
    qs[nn * HD_ + d] = QKV[((size_t)(b * S_ + n0 + nn)) * QKVW_ + d];
  }
  __syncthreads();

  // ---- phase 0b: scores into PL (k loaded once per (h,m), reused across 4 n's) ----
  for (int p = tid; p < H_ * S_; p += 256) {
    int h = p / S_, m = p - h * S_;
    const float* kp = QKV + ((size_t)(b * S_ + m)) * QKVW_ + 128 + h * D_;
    f32x4 k0 = *(const f32x4*)(kp + 0);
    f32x4 k1 = *(const f32x4*)(kp + 4);
    f32x4 k2 = *(const f32x4*)(kp + 8);
    f32x4 k3 = *(const f32x4*)(kp + 12);
    #pragma unroll
    for (int nn = 0; nn < NCH_; ++nn) {
      const float* q = qs + nn * HD_ + h * D_;
      float a = 0.f;
      #pragma unroll
      for (int c = 0; c < 4; ++c) a += q[c] * k0[c];
      #pragma unroll
      for (int c = 0; c < 4; ++c) a += q[4 + c] * k1[c];
      #pragma unroll
      for (int c = 0; c < 4; ++c) a += q[8 + c] * k2[c];
      #pragma unroll
      for (int c = 0; c < 4; ++c) a += q[12 + c] * k3[c];
      PL[nn][h][m] = a;
    }
  }
  __syncthreads();

  // ---- phase 1: per-slot loads (scores from PL; RA per MODE), then MLP ----
  {
    float cc[4][TWOH_];
    int   mm[4], nnv[4];
    bool  val[4];
    #pragma unroll
    for (int s = 0; s < 4; ++s) {
      int e = tid + s * 256;
      val[s] = (e < NV * S_);
      int nn = e / S_;
      int m  = e - nn * S_;
      if (!val[s]) { nn = 0; m = 0; }   // clamp: address stays in-bounds
      nnv[s] = nn; mm[s] = m;
      size_t eidx = ((size_t)b * S_ + (n0 + nn)) * S_ + m;
      if (MODE == 0) {
        const float* rap = RA + (((size_t)b * H_) * S_ + (n0 + nn)) * S_ + m;
        ushort8 rv;
        #pragma unroll
        for (int h = 0; h < H_; ++h) {
          bf16 bv = __float2bfloat16(rap[(size_t)h * S_ * S_]);
          rv[h] = __builtin_bit_cast(unsigned short, bv);
          unsigned int u = ((unsigned int)rv[h]) << 16;
          cc[s][H_ + h] = __builtin_bit_cast(float, u);
        }
        if (val[s]) *reinterpret_cast<ushort8*>(RAT + eidx * H_) = rv;
      } else {
        ushort8 rv = *reinterpret_cast<const ushort8*>(RAT + eidx * H_);
        #pragma unroll
        for (int h = 0; h < H_; ++h) {
          unsigned int u = ((unsigned int)rv[h]) << 16;
          cc[s][H_ + h] = __builtin_bit_cast(float, u);
        }
      }
      #pragma unroll
      for (int h = 0; h < H_; ++h) cc[s][h] = PL[nn][h][m];
    }
    #pragma unroll
    for (int s = 0; s < 4; ++s) {
      if (!val[s]) continue;
      float h1[TWOH_];
      #pragma unroll
      for (int j = 0; j < TWOH_; ++j) h1[j] = A1b[j];        // uniform -> s_load
      #pragma unroll
      for (int i = 0; i < TWOH_; ++i) {
        float c = cc[s][i];
        #pragma unroll
        for (int j = 0; j < TWOH_; ++j)
          h1[j] += c * A1w[i * TWOH_ + j];                   // uniform -> SGPR operand
      }
      float agg[H_];
      #pragma unroll
      for (int h = 0; h < H_; ++h) agg[h] = A2b[h];
      #pragma unroll
      for (int j = 0; j < TWOH_; ++j) {
        float r = fmaxf(h1[j], 0.f);
        #pragma unroll
        for (int h = 0; h < H_; ++h)
          agg[h] += r * A2w[j * H_ + h];
      }
      #pragma unroll
      for (int h = 0; h < H_; ++h) PL[nnv[s]][h][mm[s]] = agg[h];
    }
  }
  __syncthreads();

  // ---- phase 2: softmax over m; 32 groups (nn,h) x 8 lanes ----
  {
    int g = tid >> 3, lane = tid & 7;
    int nn = g >> 3, h = g & 7;
    if (nn < NV) {
      float mx = -1e30f;
      for (int m = lane; m < S_; m += 8) mx = fmaxf(mx, PL[nn][h][m]);
      #pragma unroll
      for (int off = 4; off > 0; off >>= 1) mx = fmaxf(mx, __shfl_xor(mx, off, 8));
      float sum = 0.f;
      for (int m = lane; m < S_; m += 8) {
        float e = __expf(PL[nn][h][m] - mx);
        PL[nn][h][m] = e;
        sum += e;
      }
      #pragma unroll
      for (int off = 4; off > 0; off >>= 1) sum += __shfl_xor(sum, off, 8);
      if (lane == 0) inv[nn * H_ + h] = 1.f / sum;
    }
  }
  __syncthreads();

  // ---- phase 3: PV, all 256 threads: (m-parity) x (h,d), 4 n-accumulators per V load ----
  float (*partial)[NCH_][H_][D_] = (float (*)[NCH_][H_][D_])shbuf;
  {
    int half = tid >> 7, h = (tid >> 4) & 7, d = tid & 15;
    float a0 = 0.f, a1 = 0.f, a2 = 0.f, a3 = 0.f;
    const float* vp = QKV + (size_t)b * S_ * QKVW_ + 256 + h * D_ + d;
    for (int m = half; m < S_; m += 2) {
      float vv = vp[(size_t)m * QKVW_];
      a0 += PL[0][h][m] * vv;
      a1 += PL[1][h][m] * vv;
      a2 += PL[2][h][m] * vv;
      a3 += PL[3][h][m] * vv;
    }
    partial[half][0][h][d] = a0;
    partial[half][1][h][d] = a1;
    partial[half][2][h][d] = a2;
    partial[half][3][h][d] = a3;
  }
  __syncthreads();
  if (tid < 128) {
    int h = tid >> 4, d = tid & 15;
    #pragma unroll
    for (int nn = 0; nn < NCH_; ++nn)
      if (nn < NV) {
        float s = (partial[0][nn][h][d] + partial[1][nn][h][d]) * inv[nn * H_ + h];
        bf16* ob = (bf16*)(QKV + (size_t)(b * S_ + n0 + nn) * QKVW_);
        bf16 sh, sl;
        split_bf16(s, sh, sl);
        ob[h * D_ + d]       = sh;   // OBh in Q cols [0,64) f32
        ob[128 + h * D_ + d] = sl;   // OBl in Q cols [64,128) f32
      }
  }
}

// ---------------- instance norm, (B,4) grid: 32 channels per block ----------------
__global__ __launch_bounds__(128) void inorm_kernel(const float* __restrict__ Y,
                                                    const float* __restrict__ w,
                                                    const float* __restrict__ bb,
                                                    float* __restrict__ X,
                                                    bf16* __restrict__ XBh,
                                                    bf16* __restrict__ XBl) {
  int b = blockIdx.x;
  int e0 = blockIdx.y * 32;
  int tid = threadIdx.x;
  int el = tid & 31, sg = tid >> 5;   // 4 s-groups x 32 channels
  int e = e0 + el;
  __shared__ float ps[4][32], pss[4][32];
  const float* base = Y + (size_t)b * S_ * E_;
  float s = 0.f, ss = 0.f;
  for (int i = sg; i < S_; i += 4) {
    float v = base[(size_t)i * E_ + e];
    s += v; ss += v * v;
  }
  ps[sg][el] = s; pss[sg][el] = ss;
  __syncthreads();
  if (sg == 0) {
    s  = ps[0][el] + ps[1][el] + ps[2][el] + ps[3][el];
    ss = pss[0][el] + pss[1][el] + pss[2][el] + pss[3][el];
    float mean = s / S_;
    float var  = fmaxf(ss / S_ - mean * mean, 0.f);
    float scale = rsqrtf(var + 1e-5f) * w[e];
    ps[0][el]  = scale;
    pss[0][el] = bb[e] - mean * scale;
  }
  __syncthreads();
  float scale = ps[0][el], shift = pss[0][el];
  float* dst = X + (size_t)b * S_ * E_;
  for (int i = sg; i < S_; i += 4) {
    size_t idx = (size_t)i * E_ + e;
    float v = base[idx] * scale + shift;
    dst[idx] = v;
    if (XBh) {
      size_t gi = (size_t)b * S_ * E_ + idx;
      bf16 vh, vl;
      split_bf16(v, vh, vl);
      XBh[gi] = vh;
      XBl[gi] = vl;
    }
  }
}

extern "C" void kernel_launch(void* const* d_in, const int* in_sizes, int n_in,
                              void* d_out, int out_size, void* d_ws, size_t ws_size,
                              hipStream_t stream) {
  const float* depot = (const float*)d_in[0];
  const float* node  = (const float*)d_in[1];
  const float* RA    = (const float*)d_in[2];
  const float* Wd    = (const float*)d_in[3];
  const float* bd    = (const float*)d_in[4];
  const float* Wn    = (const float*)d_in[5];
  const float* bn    = (const float*)d_in[6];
  const float* Wq    = (const float*)d_in[7];
  const float* Wk    = (const float*)d_in[8];
  const float* Wv    = (const float*)d_in[9];
  const float* Wo    = (const float*)d_in[10];
  const float* bo    = (const float*)d_in[11];
  const float* A1w   = (const float*)d_in[12];
  const float* A1b   = (const float*)d_in[13];
  const float* A2w   = (const float*)d_in[14];
  const float* A2b   = (const float*)d_in[15];
  const float* n1w   = (const float*)d_in[16];
  const float* n1b   = (const float*)d_in[17];
  const float* n2w   = (const float*)d_in[18];
  const float* n2b   = (const float*)d_in[19];
  const float* F1w   = (const float*)d_in[20];
  const float* F1b   = (const float*)d_in[21];
  const float* F2w   = (const float*)d_in[22];
  const float* F2b   = (const float*)d_in[23];

  const size_t XSZ  = (size_t)B_ * S_ * E_;        // 1,646,592
  const size_t SCSZ = (size_t)B_ * H_ * S_ * S_;   // 20,685,312 (scratch region)
  const size_t XBF  = XSZ / 2;                     // bf16 buffer in float-slots: 823,296
  float* ws = (float*)d_ws;
  float* X   = ws;                    // f32 [M][E]
  float* QKV = ws + XSZ;              // f32 [M][384] packed Q|K|V (OB reuses dead Q cols)
  float* SCR = ws + 4 * XSZ;          // scratch region:
  float* TMP = SCR;                                  // f32 [0, XSZ)
  bf16*  XBh = (bf16*)(SCR + XSZ);                   // M*E bf16
  bf16*  XBl = (bf16*)(SCR + XSZ + XBF);
  bf16*  HBh = (bf16*)(SCR + XSZ + 2 * XBF);         // M*FF bf16 (4 XBF span)
  bf16*  HBl = (bf16*)(SCR + XSZ + 6 * XBF);
  bf16*  RAT = (bf16*)(SCR + XSZ + 10 * XBF);        // B*S*S*H bf16 (10.34M slots, fits SCSZ)
  float* tail = ws + 4 * XSZ + SCSZ;
  bf16*  WTh = (bf16*)tail;                          // 1,179,648 bf16 = 589,824 fl
  bf16*  WTl = (bf16*)(tail + 589824);
  // ws use: 4*XSZ + SCSZ + 1,179,648 floats = 28,451,328 fl = 113.8 MB
  const bf16* OBh = (const bf16*)QKV;        // strided lda=768 (row = 384 f32)
  const bf16* OBl = (const bf16*)QKV + 128;

  const int M = B_ * S_;  // 12864 = 201*64

  wcvt_kernel<<<4608, 256, 0, stream>>>(Wo, F1w, F2w, Wq, Wk, Wv, WTh, WTl);
  embed_kernel<<<(B_ * S_ * E_ + 255) / 256, 256, 0, stream>>>(depot, node, Wd, bd, Wn, bn, X, XBh, XBl);

  for (int l = 0; l < L_; ++l) {
    // QKV fused: [M][384] = XB @ [Wq|Wk|Wv]  (split precision)
    mgemm_kernel<3><<<dim3(M / 64, 6), 256, 0, stream>>>(
        XBh, XBl, WTh + 884736 + (size_t)l * 49152, WTl + 884736 + (size_t)l * 49152,
        nullptr, nullptr, QKV, nullptr, nullptr, E_, QKVW_, E_);
    // fused inline-score + edge-MLP + softmax + PV
    // layer 0: scattered RA read + RAT write; layers 1+: coalesced RAT read
    if (l == 0)
      attn_kernel<0><<<B_ * NCHB_, 256, 0, stream>>>(RA, RAT,
          A1w + (size_t)l * TWOH_ * TWOH_, A1b + (size_t)l * TWOH_,
          A2w + (size_t)l * TWOH_ * H_,    A2b + (size_t)l * H_, QKV);
    else
      attn_kernel<1><<<B_ * NCHB_, 256, 0, stream>>>(RA, RAT,
          A1w + (size_t)l * TWOH_ * TWOH_, A1b + (size_t)l * TWOH_,
          A2w + (size_t)l * TWOH_ * H_,    A2b + (size_t)l * H_, QKV);
    // Wo: TMP = OB @ WoT^T + bo + X   (split precision; A strided in QKV rows)
    mgemm_kernel<1><<<dim3(M / 64, 2), 256, 0, stream>>>(
        OBh, OBl, WTh + (size_t)l * 16384, WTl + (size_t)l * 16384,
        bo + (size_t)l * E_, X, TMP, nullptr, nullptr, HD_, E_, 768);
    inorm_kernel<<<dim3(B_, 4), 128, 0, stream>>>(TMP, n1w + (size_t)l * E_, n1b + (size_t)l * E_, X, XBh, XBl);
    // F1: HB = relu(XB @ F1T^T + F1b)  (split bf16 out)
    mgemm_kernel<2><<<dim3(M / 64, 8), 256, 0, stream>>>(
        XBh, XBl, WTh + 98304 + (size_t)l * 65536, WTl + 98304 + (size_t)l * 65536,
        F1b + (size_t)l * FF_, nullptr, nullptr, HBh, HBl, E_, FF_, E_);
    // F2: TMP = HB @ F2T^T + F2b + X
    mgemm_kernel<1><<<dim3(M / 64, 2), 256, 0, stream>>>(
        HBh, HBl, WTh + 491520 + (size_t)l * 65536, WTl + 491520 + (size_t)l * 65536,
        F2b + (size_t)l * E_, X, TMP, nullptr, nullptr, FF_, E_, FF_);
    float* dst = (l == L_ - 1) ? (float*)d_out : X;
    bf16* xh = (l == L_ - 1) ? nullptr : XBh;
    bf16* xl = (l == L_ - 1) ? nullptr : XBl;
    inorm_kernel<<<dim3(B_, 4), 128, 0, stream>>>(TMP, n2w + (size_t)l * E_, n2b + (size_t)l * E_, dst, xh, xl);
  }
}